// Round 1
// baseline (645.111 us; speedup 1.0000x reference)
//
#include <hip/hip_runtime.h>
#include <math.h>

// ---------------------------------------------------------------------------
// EMD layer (Sinkhorn-OT logits) for MI355X.
// support: [32,512,8,8] f32, query: [256,512,8,8] f32 -> logits [256,32] f32.
//
// R12: emd occupancy fix. rocprof showed emd at Occupancy 35% / VALUBusy 49%
//      with LDS 34.8KB capping residency at 4 blocks/CU (16 waves) and the
//      2048-block grid running in TWO occupancy rounds with ragged Sinkhorn
//      tails. The T[2] double buffer only serves the ONE-TIME phase-2
//      exp/transpose roundtrip -> single 17,408B buffer, 4 serial rounds
//      (one wave at a time). 8 blocks/CU => whole grid co-resident, VALU
//      latency chains hidden by 8 waves/SIMD. __launch_bounds__(256,8)
//      pins VGPR<=64 (currently exactly 64). Output bit-identical to R11.
//      norm and marg unchanged.
// ---------------------------------------------------------------------------

#define DEV static __device__ __forceinline__

typedef _Float16 half8 __attribute__((ext_vector_type(8)));
typedef float floatx4 __attribute__((ext_vector_type(4)));

DEV float fast_rcp(float x) {
#if __has_builtin(__builtin_amdgcn_rcpf)
    return __builtin_amdgcn_rcpf(x);
#else
    return 1.0f / x;
#endif
}
DEV float fexp2(float x) {
#if __has_builtin(__builtin_amdgcn_exp2f)
    return __builtin_amdgcn_exp2f(x);
#else
    return exp2f(x);
#endif
}
DEV float flog2(float x) {
#if __has_builtin(__builtin_amdgcn_logf)
    return __builtin_amdgcn_logf(x);
#else
    return log2f(x);
#endif
}

#define K_SIM2M 28.853900817779268f    // 20/ln2 : M = 2^((sim-1)*K_SIM2M)
#define K_M2SIM 0.034657359027997264f  // 0.05*ln2 : sim = 1 + log2(M)*K_M2SIM
#define LDP 68                         // padded LDS row stride (floats)

// ------ K1: center+normalize over C -> fp16 FRAGMENT order, + pool stats ----
// 1024 threads: 16 waves. Fragment chunk (kk,t,slot) = channels
// kk*32+(slot>>4)*8..+8 of node t*16+(slot&15), at ((kk*4+t)*64+slot)*8 halves.
__global__ void __launch_bounds__(1024, 1)
norm_kernel(const float* __restrict__ support, const float* __restrict__ query,
            _Float16* __restrict__ Vht, _Float16* __restrict__ Uht,
            float* __restrict__ BpT, float* __restrict__ QpT,
            float* __restrict__ muA, float* __restrict__ nrmA,
            float* __restrict__ Ssc) {
    __shared__ float red1[16][64];
    __shared__ float red2[16][64];
    __shared__ float muL[64], invL[64];
    __shared__ float tile[128][65];

    int sid = blockIdx.x;             // 0..287
    const float* src;
    _Float16* dst;
    float* poolT;
    int pstride, pidx;
    if (sid < 32) {
        src = support + (size_t)sid * 32768; dst = Vht + (size_t)sid * 32768;
        poolT = BpT; pstride = 32; pidx = sid;
    } else {
        src = query + (size_t)(sid - 32) * 32768; dst = Uht + (size_t)(sid - 32) * 32768;
        poolT = QpT; pstride = 256; pidx = sid - 32;
    }

    int node = threadIdx.x & 63;
    int cq   = threadIdx.x >> 6;      // wave index 0..15

    // ---- stats pass: each wave handles 32 channels ----
    float s1 = 0.f, s2 = 0.f;
#pragma unroll 8
    for (int j = 0; j < 32; ++j) {
        int c = cq * 32 + j;
        float x = src[c * 64 + node];
        s1 += x; s2 += x * x;
        float ps = x;                  // pool: sum over the wave's 64 nodes
        ps += __shfl_xor(ps, 1);  ps += __shfl_xor(ps, 2);  ps += __shfl_xor(ps, 4);
        ps += __shfl_xor(ps, 8);  ps += __shfl_xor(ps, 16); ps += __shfl_xor(ps, 32);
        if (node == 0) poolT[(size_t)c * pstride + pidx] = ps * (1.0f / 64.0f);
    }
    red1[cq][node] = s1;
    red2[cq][node] = s2;
    __syncthreads();
    if (threadIdx.x < 64) {
        float t1 = 0.f, t2 = 0.f;
#pragma unroll
        for (int k = 0; k < 16; ++k) { t1 += red1[k][node]; t2 += red2[k][node]; }
        float mu  = t1 * (1.0f / 512.0f);
        float ss  = t2 - 512.0f * mu * mu;
        float nrm = fmaxf(sqrtf(fmaxf(ss, 0.0f)), 1e-8f);
        muL[node]  = mu;
        invL[node] = 1.0f / nrm;
        muA[sid * 64 + node]  = mu;
        nrmA[sid * 64 + node] = nrm;
        float sS = t1;                 // S = sum_c pool[c]
        sS += __shfl_xor(sS, 1);  sS += __shfl_xor(sS, 2);  sS += __shfl_xor(sS, 4);
        sS += __shfl_xor(sS, 8);  sS += __shfl_xor(sS, 16); sS += __shfl_xor(sS, 32);
        if (node == 0) Ssc[sid] = sS * (1.0f / 64.0f);
    }
    __syncthreads();

    // ---- normalize + fragment-order write, slab = 128 channels ----
    float mu = muL[node], inv = invL[node];
    for (int ch = 0; ch < 4; ++ch) {
#pragma unroll
        for (int j = 0; j < 8; ++j) {
            int cl = cq * 8 + j;       // 16 waves x 8 = 128 channels
            float x = src[(ch * 128 + cl) * 64 + node];
            tile[cl][node] = (x - mu) * inv;
        }
        __syncthreads();
        // 1024 fragment chunks per slab: exactly one per thread
        {
            int g    = threadIdx.x;    // kkl*256 + t*64 + slot
            int slot = g & 63;
            int t    = (g >> 6) & 3;
            int kkl  = g >> 8;
            int nd   = t * 16 + (slot & 15);
            int c8   = (kkl << 2) | (slot >> 4);
            half8 v;
#pragma unroll
            for (int i = 0; i < 8; ++i) v[i] = (_Float16)tile[c8 * 8 + i][nd];
            *(half8*)(dst + ((size_t)ch * 1024 + g) * 8) = v;
        }
        __syncthreads();
    }
}

// --------- K2: merged a/b marginals from fragment-order fp16 ----------------
// raw_dot = nrm * <fp16 normalized vec, pooled vec> + mu * S(pooled vec)
__global__ void __launch_bounds__(256)
marg_kernel(const _Float16* __restrict__ Uht, const _Float16* __restrict__ Vht,
            const float* __restrict__ BpT, const float* __restrict__ QpT,
            const float* __restrict__ muA, const float* __restrict__ nrmA,
            const float* __restrict__ Ssc,
            float* __restrict__ a_out, float* __restrict__ b_out) {
    __shared__ __align__(16) float WL[512 * 32];   // [c][k] 64 KB
    __shared__ float Sl[32];
    int lane = threadIdx.x & 63;   // node
    int kq   = threadIdx.x >> 6;   // k = kq*8 .. +7

    const _Float16* src16;
    float mu, nrm;
    if (blockIdx.x < 256) {
        // a-marginals: block per q (XCD-grouped), k enumerates w (32)
        int q = (blockIdx.x & 7) * 32 + (blockIdx.x >> 3);
        for (int t = threadIdx.x; t < 4096; t += 256)
            ((float4*)WL)[t] = ((const float4*)BpT)[t];
        if (threadIdx.x < 32) Sl[threadIdx.x] = Ssc[threadIdx.x];  // S_w
        src16 = Uht + (size_t)q * 32768;
        mu  = muA[(32 + q) * 64 + lane];
        nrm = nrmA[(32 + q) * 64 + lane];
    } else {
        // b-marginals: block per (w, q-group of 32), k enumerates qlocal
        int id = blockIdx.x - 256;
        int w = id >> 3, qg = id & 7;
        for (int t = threadIdx.x; t < 4096; t += 256) {
            int c = t >> 3, k = t & 7;
            ((float4*)WL)[t] = ((const float4*)(QpT + (size_t)c * 256 + qg * 32))[k];
        }
        if (threadIdx.x < 32) Sl[threadIdx.x] = Ssc[32 + qg * 32 + threadIdx.x]; // S'_q
        src16 = Vht + (size_t)w * 32768;
        mu  = muA[w * 64 + lane];
        nrm = nrmA[w * 64 + lane];
    }
    __syncthreads();

    // lane's node-n data: chunk (kk, t=n>>4, slot=(hi<<4)|(n&15)) = c kk*32+hi*8..+8
    int lbase = (lane >> 4) * 64 + (lane & 15);
    float acc[8] = {0, 0, 0, 0, 0, 0, 0, 0};
#pragma unroll 1
    for (int kk = 0; kk < 16; ++kk) {
#pragma unroll
        for (int hi = 0; hi < 4; ++hi) {
            half8 x8 = *(const half8*)(src16 +
                        ((size_t)(kk * 256 + lbase + (hi << 4)) * 8));
            int cb = kk * 32 + hi * 8;
#pragma unroll
            for (int j = 0; j < 8; ++j) {
                float xv = (float)x8[j];
                const float* wl = WL + (cb + j) * 32 + kq * 8;
                float4 b0 = *(const float4*)wl;
                float4 b1 = *(const float4*)(wl + 4);
                acc[0] = fmaf(xv, b0.x, acc[0]); acc[1] = fmaf(xv, b0.y, acc[1]);
                acc[2] = fmaf(xv, b0.z, acc[2]); acc[3] = fmaf(xv, b0.w, acc[3]);
                acc[4] = fmaf(xv, b1.x, acc[4]); acc[5] = fmaf(xv, b1.y, acc[5]);
                acc[6] = fmaf(xv, b1.z, acc[6]); acc[7] = fmaf(xv, b1.w, acc[7]);
            }
        }
    }
#pragma unroll
    for (int k = 0; k < 8; ++k) {
        float raw = fmaf(mu, Sl[kq * 8 + k], nrm * acc[k]);
        float v = fmaxf(raw, 0.0f) + 0.001f;
        v += 1e-5f;
        float s = v;
        s += __shfl_xor(s, 1);  s += __shfl_xor(s, 2);  s += __shfl_xor(s, 4);
        s += __shfl_xor(s, 8);  s += __shfl_xor(s, 16); s += __shfl_xor(s, 32);
        v = v * (64.0f / s);
        if (blockIdx.x < 256) {
            int q = (blockIdx.x & 7) * 32 + (blockIdx.x >> 3), w = kq * 8 + k;
            a_out[((size_t)q * 32 + w) * 64 + lane] = v;
        } else {
            int id = blockIdx.x - 256;
            int w = id >> 3, q = (id & 7) * 32 + kq * 8 + k;
            b_out[((size_t)w * 256 + q) * 64 + lane] = v;
        }
    }
}

// --------- K3: FUSED MFMA sim + exp/transpose + Sinkhorn + logits -----------
// Wave per (q,w). XCD-resident: blockIdx%8 = XCD handles one q-group.
// R12: single 17.4KB LDS buffer (phase 2 serialized over the 4 waves) =>
// 8 blocks/CU resident (32 waves/CU), whole 2048-block grid in one round.
__global__ void __launch_bounds__(256, 8)
emd_kernel(const _Float16* __restrict__ Uht, const _Float16* __restrict__ Vht,
           const float* __restrict__ a_arr, const float* __restrict__ b_arr,
           float* __restrict__ out) {
    __shared__ __align__(16) float T[64 * LDP];      // 17.4 KB

    int x    = blockIdx.x & 7;
    int i    = blockIdx.x >> 3;
    int w    = i & 31;
    int wave = threadIdx.x >> 6;
    int lane = threadIdx.x & 63;
    int q    = (x * 8 + (i >> 5)) * 4 + wave;        // XCD x: q in [32x,32x+32)
    int lo16 = lane & 15;
    int hi4  = lane >> 4;
    int ig   = lane >> 3;
    int jg   = lane & 7;

    // ---- phase 1: sim tile via fp16 MFMA, fragment-order loads ----
    floatx4 acc[4][4];
#pragma unroll
    for (int tm = 0; tm < 4; ++tm)
#pragma unroll
        for (int tn = 0; tn < 4; ++tn)
            acc[tm][tn] = (floatx4){0.f, 0.f, 0.f, 0.f};

    const _Float16* Abase = Uht + (size_t)q * 32768 + lane * 8;
    const _Float16* Bbase = Vht + (size_t)w * 32768 + lane * 8;
#pragma unroll 1
    for (int kk = 0; kk < 16; ++kk) {
        half8 bf[4];
#pragma unroll
        for (int t = 0; t < 4; ++t)
            bf[t] = *(const half8*)(Bbase + (size_t)(kk * 4 + t) * 512);
#pragma unroll
        for (int tm = 0; tm < 4; ++tm) {
            half8 af = *(const half8*)(Abase + (size_t)(kk * 4 + tm) * 512);
#pragma unroll
            for (int tn = 0; tn < 4; ++tn)
                acc[tm][tn] = __builtin_amdgcn_mfma_f32_16x16x32_f16(
                    af, bf[tn], acc[tm][tn], 0, 0, 0);
        }
    }

    // ---- wave-uniform tile max for the fp16 rescale ----
    float lmax = -2.0f;
#pragma unroll
    for (int tm = 0; tm < 4; ++tm)
#pragma unroll
        for (int tn = 0; tn < 4; ++tn)
#pragma unroll
            for (int r = 0; r < 4; ++r) lmax = fmaxf(lmax, acc[tm][tn][r]);
    lmax = fmaxf(lmax, __shfl_xor(lmax, 1));
    lmax = fmaxf(lmax, __shfl_xor(lmax, 2));
    lmax = fmaxf(lmax, __shfl_xor(lmax, 4));
    lmax = fmaxf(lmax, __shfl_xor(lmax, 8));
    lmax = fmaxf(lmax, __shfl_xor(lmax, 16));
    lmax = fmaxf(lmax, __shfl_xor(lmax, 32));
    float s0 = lmax;

    // ---- phase 2: exp + LDS roundtrip into xor-permuted layout, fp16 ----
    // Single buffer, one wave at a time (runs ONCE; LDS capacity buys
    // 8 blocks/CU for the per-iteration Sinkhorn phase below).
    half8 Mh[8];
#pragma unroll 1
    for (int round = 0; round < 4; ++round) {
        if (wave == round) {
            float* buf = T;
#pragma unroll
            for (int tm = 0; tm < 4; ++tm)
#pragma unroll
                for (int tn = 0; tn < 4; ++tn)
#pragma unroll
                    for (int r = 0; r < 4; ++r) {
                        int row = tm * 16 + hi4 * 4 + r;
                        int col = tn * 16 + lo16;
                        int sp  = (col & 7) ^ (row >> 3);
                        buf[row * LDP + (col & ~7) + sp] =
                            fexp2((acc[tm][tn][r] - s0) * K_SIM2M);
                    }
        }
        __syncthreads();
        if (wave == round) {
            const float* buf = T;
#pragma unroll
            for (int t = 0; t < 8; ++t) {
                const float* p = buf + (ig * 8 + (jg ^ t)) * LDP + jg * 8;
                float4 m0 = *(const float4*)p;
                float4 m1 = *(const float4*)(p + 4);
                half8 h;
                h[0] = (_Float16)m0.x; h[1] = (_Float16)m0.y;
                h[2] = (_Float16)m0.z; h[3] = (_Float16)m0.w;
                h[4] = (_Float16)m1.x; h[5] = (_Float16)m1.y;
                h[6] = (_Float16)m1.z; h[7] = (_Float16)m1.w;
                Mh[t] = h;
            }
        }
        __syncthreads();
    }

    // ---- phase 3: Sinkhorn, reduce-scatter + all-gather, tol early exit ----
    int gp = q * 32 + w;
    float a_own = a_arr[(size_t)gp * 64 + ig * 8 + jg];
    float b_own = b_arr[((size_t)w * 256 + q) * 64 + jg * 8 + ig];

    float wvp[8];
#pragma unroll
    for (int s = 0; s < 8; ++s) wvp[s] = 1.0f;
    float q8[8];
    float w_prev = -1.f;

#pragma unroll 1
    for (int it = 0; it < 100; ++it) {
        float p[8];
#pragma unroll
        for (int t = 0; t < 8; ++t) {
            float s = (float)Mh[t][0] * wvp[0];
#pragma unroll
            for (int c = 1; c < 8; ++c) s = fmaf((float)Mh[t][c], wvp[c], s);
            p[t] = s;
        }
        p[0] += __shfl_xor(p[4], 4); p[1] += __shfl_xor(p[5], 4);
        p[2] += __shfl_xor(p[6], 4); p[3] += __shfl_xor(p[7], 4);
        p[0] += __shfl_xor(p[2], 2); p[1] += __shfl_xor(p[3], 2);
        p[0] += __shfl_xor(p[1], 1);
        float z_own = a_own * fast_rcp(p[0]);
        q8[0] = z_own;
        q8[1] = __shfl_xor(q8[0], 1);
        q8[2] = __shfl_xor(q8[0], 2); q8[3] = __shfl_xor(q8[1], 2);
        q8[4] = __shfl_xor(q8[0], 4); q8[5] = __shfl_xor(q8[1], 4);
        q8[6] = __shfl_xor(q8[2], 4); q8[7] = __shfl_xor(q8[3], 4);
        float cp[8];
#pragma unroll
        for (int s = 0; s < 8; ++s) {
            float v = (float)Mh[0][s] * q8[0];
#pragma unroll
            for (int t = 1; t < 8; ++t) v = fmaf((float)Mh[t][s], q8[t], v);
            cp[s] = v;
        }
        cp[0] += __shfl_xor(cp[4], 32); cp[1] += __shfl_xor(cp[5], 32);
        cp[2] += __shfl_xor(cp[6], 32); cp[3] += __shfl_xor(cp[7], 32);
        cp[0] += __shfl_xor(cp[2], 16); cp[1] += __shfl_xor(cp[3], 16);
        cp[0] += __shfl_xor(cp[1], 8);
        float w_own = b_own * fast_rcp(cp[0]);
        wvp[0] = w_own;
        wvp[1] = __shfl_xor(wvp[0], 8);
        wvp[2] = __shfl_xor(wvp[0], 16); wvp[3] = __shfl_xor(wvp[1], 16);
        wvp[4] = __shfl_xor(wvp[0], 32); wvp[5] = __shfl_xor(wvp[1], 32);
        wvp[6] = __shfl_xor(wvp[2], 32); wvp[7] = __shfl_xor(wvp[3], 32);
        // w stable across all 64 cols -> next z,w identical -> fixed point
        bool same = fabsf(w_own - w_prev) <= 1e-5f * w_own;
        w_prev = w_own;
        if (__all(same)) break;
    }

    // ---- phase 4: logits; sim = s0 + log2(M')*eps*ln2 ----
    float s = 0.f;
#pragma unroll
    for (int t = 0; t < 8; ++t)
#pragma unroll
        for (int c = 0; c < 8; ++c) {
            float m    = fmaxf((float)Mh[t][c], 1e-30f);
            float sim  = fmaf(flog2(m), K_M2SIM, s0);
            float flow = q8[t] * m * wvp[c];
            s = fmaf(sim, flow, s);
        }
    s += __shfl_xor(s, 1);  s += __shfl_xor(s, 2);  s += __shfl_xor(s, 4);
    s += __shfl_xor(s, 8);  s += __shfl_xor(s, 16); s += __shfl_xor(s, 32);
    if (lane == 0) out[gp] = s * 0.1953125f;   // 12.5/64
}

// ---------------------------------------------------------------------------
extern "C" void kernel_launch(void* const* d_in, const int* in_sizes, int n_in,
                              void* d_out, int out_size, void* d_ws, size_t ws_size,
                              hipStream_t stream) {
    (void)in_sizes; (void)n_in; (void)out_size; (void)ws_size;
    const float* support = (const float*)d_in[0];   // 32*512*64
    const float* query   = (const float*)d_in[1];   // 256*512*64

    char* ws = (char*)d_ws;
    _Float16* Uht = (_Float16*)ws;                  // 16 MB (fragment order)
    _Float16* Vht = Uht + 8388608;                  //  2 MB (fragment order)
    float* BpT  = (float*)(Vht + 1048576);          // 64 KB  [512][32]
    float* QpT  = BpT + 16384;                      // 512 KB [512][256]
    float* aA   = QpT + 131072;                     //  2 MB
    float* bA   = aA + 524288;                      //  2 MB
    float* muA  = bA + 524288;                      // 72 KB [288][64]
    float* nrmA = muA + 18432;                      // 72 KB
    float* Ssc  = nrmA + 18432;                     // ~1 KB [288]  (~23 MB total)

    norm_kernel<<<288, 1024, 0, stream>>>(support, query, Vht, Uht, BpT, QpT,
                                          muA, nrmA, Ssc);
    marg_kernel<<<512, 256, 0, stream>>>(Uht, Vht, BpT, QpT, muA, nrmA, Ssc,
                                         aA, bA);
    emd_kernel<<<2048, 256, 0, stream>>>(Uht, Vht, aA, bA, (float*)d_out);
}

// Round 2
// 209.855 us; speedup vs baseline: 3.0741x; 3.0741x over previous
//
#include <hip/hip_runtime.h>
#include <math.h>

// ---------------------------------------------------------------------------
// EMD layer (Sinkhorn-OT logits) for MI355X.
// support: [32,512,8,8] f32, query: [256,512,8,8] f32 -> logits [256,32] f32.
//
// R13: R12 reverted (launch_bounds(256,8) forced 64-reg budget -> massive
//      scratch spill, FETCH 18.5MB->950MB, 70->515us). Real limiter is the
//      Sinkhorn VALU: 128 v_cvt_f32_f16 per iteration from the f16 M copy.
//      M now stays f32 in registers (Mf[8][8], 64 VGPRs) -- the acc[4][4]
//      AGPRs are dead by phase 3, so lifetimes overlap inside the 128-reg
//      budget of launch_bounds(256,4). Cuts hot-loop VALU ~2x and removes
//      f16 rounding of M (accuracy improves). norm/marg = R11 unchanged.
// ---------------------------------------------------------------------------

#define DEV static __device__ __forceinline__

typedef _Float16 half8 __attribute__((ext_vector_type(8)));
typedef float floatx4 __attribute__((ext_vector_type(4)));

DEV float fast_rcp(float x) {
#if __has_builtin(__builtin_amdgcn_rcpf)
    return __builtin_amdgcn_rcpf(x);
#else
    return 1.0f / x;
#endif
}
DEV float fexp2(float x) {
#if __has_builtin(__builtin_amdgcn_exp2f)
    return __builtin_amdgcn_exp2f(x);
#else
    return exp2f(x);
#endif
}
DEV float flog2(float x) {
#if __has_builtin(__builtin_amdgcn_logf)
    return __builtin_amdgcn_logf(x);
#else
    return log2f(x);
#endif
}

#define K_SIM2M 28.853900817779268f    // 20/ln2 : M = 2^((sim-1)*K_SIM2M)
#define K_M2SIM 0.034657359027997264f  // 0.05*ln2 : sim = 1 + log2(M)*K_M2SIM
#define LDP 68                         // padded LDS row stride (floats)

// ------ K1: center+normalize over C -> fp16 FRAGMENT order, + pool stats ----
// 1024 threads: 16 waves. Fragment chunk (kk,t,slot) = channels
// kk*32+(slot>>4)*8..+8 of node t*16+(slot&15), at ((kk*4+t)*64+slot)*8 halves.
__global__ void __launch_bounds__(1024, 1)
norm_kernel(const float* __restrict__ support, const float* __restrict__ query,
            _Float16* __restrict__ Vht, _Float16* __restrict__ Uht,
            float* __restrict__ BpT, float* __restrict__ QpT,
            float* __restrict__ muA, float* __restrict__ nrmA,
            float* __restrict__ Ssc) {
    __shared__ float red1[16][64];
    __shared__ float red2[16][64];
    __shared__ float muL[64], invL[64];
    __shared__ float tile[128][65];

    int sid = blockIdx.x;             // 0..287
    const float* src;
    _Float16* dst;
    float* poolT;
    int pstride, pidx;
    if (sid < 32) {
        src = support + (size_t)sid * 32768; dst = Vht + (size_t)sid * 32768;
        poolT = BpT; pstride = 32; pidx = sid;
    } else {
        src = query + (size_t)(sid - 32) * 32768; dst = Uht + (size_t)(sid - 32) * 32768;
        poolT = QpT; pstride = 256; pidx = sid - 32;
    }

    int node = threadIdx.x & 63;
    int cq   = threadIdx.x >> 6;      // wave index 0..15

    // ---- stats pass: each wave handles 32 channels ----
    float s1 = 0.f, s2 = 0.f;
#pragma unroll 8
    for (int j = 0; j < 32; ++j) {
        int c = cq * 32 + j;
        float x = src[c * 64 + node];
        s1 += x; s2 += x * x;
        float ps = x;                  // pool: sum over the wave's 64 nodes
        ps += __shfl_xor(ps, 1);  ps += __shfl_xor(ps, 2);  ps += __shfl_xor(ps, 4);
        ps += __shfl_xor(ps, 8);  ps += __shfl_xor(ps, 16); ps += __shfl_xor(ps, 32);
        if (node == 0) poolT[(size_t)c * pstride + pidx] = ps * (1.0f / 64.0f);
    }
    red1[cq][node] = s1;
    red2[cq][node] = s2;
    __syncthreads();
    if (threadIdx.x < 64) {
        float t1 = 0.f, t2 = 0.f;
#pragma unroll
        for (int k = 0; k < 16; ++k) { t1 += red1[k][node]; t2 += red2[k][node]; }
        float mu  = t1 * (1.0f / 512.0f);
        float ss  = t2 - 512.0f * mu * mu;
        float nrm = fmaxf(sqrtf(fmaxf(ss, 0.0f)), 1e-8f);
        muL[node]  = mu;
        invL[node] = 1.0f / nrm;
        muA[sid * 64 + node]  = mu;
        nrmA[sid * 64 + node] = nrm;
        float sS = t1;                 // S = sum_c pool[c]
        sS += __shfl_xor(sS, 1);  sS += __shfl_xor(sS, 2);  sS += __shfl_xor(sS, 4);
        sS += __shfl_xor(sS, 8);  sS += __shfl_xor(sS, 16); sS += __shfl_xor(sS, 32);
        if (node == 0) Ssc[sid] = sS * (1.0f / 64.0f);
    }
    __syncthreads();

    // ---- normalize + fragment-order write, slab = 128 channels ----
    float mu = muL[node], inv = invL[node];
    for (int ch = 0; ch < 4; ++ch) {
#pragma unroll
        for (int j = 0; j < 8; ++j) {
            int cl = cq * 8 + j;       // 16 waves x 8 = 128 channels
            float x = src[(ch * 128 + cl) * 64 + node];
            tile[cl][node] = (x - mu) * inv;
        }
        __syncthreads();
        // 1024 fragment chunks per slab: exactly one per thread
        {
            int g    = threadIdx.x;    // kkl*256 + t*64 + slot
            int slot = g & 63;
            int t    = (g >> 6) & 3;
            int kkl  = g >> 8;
            int nd   = t * 16 + (slot & 15);
            int c8   = (kkl << 2) | (slot >> 4);
            half8 v;
#pragma unroll
            for (int i = 0; i < 8; ++i) v[i] = (_Float16)tile[c8 * 8 + i][nd];
            *(half8*)(dst + ((size_t)ch * 1024 + g) * 8) = v;
        }
        __syncthreads();
    }
}

// --------- K2: merged a/b marginals from fragment-order fp16 ----------------
// raw_dot = nrm * <fp16 normalized vec, pooled vec> + mu * S(pooled vec)
__global__ void __launch_bounds__(256)
marg_kernel(const _Float16* __restrict__ Uht, const _Float16* __restrict__ Vht,
            const float* __restrict__ BpT, const float* __restrict__ QpT,
            const float* __restrict__ muA, const float* __restrict__ nrmA,
            const float* __restrict__ Ssc,
            float* __restrict__ a_out, float* __restrict__ b_out) {
    __shared__ __align__(16) float WL[512 * 32];   // [c][k] 64 KB
    __shared__ float Sl[32];
    int lane = threadIdx.x & 63;   // node
    int kq   = threadIdx.x >> 6;   // k = kq*8 .. +7

    const _Float16* src16;
    float mu, nrm;
    if (blockIdx.x < 256) {
        // a-marginals: block per q (XCD-grouped), k enumerates w (32)
        int q = (blockIdx.x & 7) * 32 + (blockIdx.x >> 3);
        for (int t = threadIdx.x; t < 4096; t += 256)
            ((float4*)WL)[t] = ((const float4*)BpT)[t];
        if (threadIdx.x < 32) Sl[threadIdx.x] = Ssc[threadIdx.x];  // S_w
        src16 = Uht + (size_t)q * 32768;
        mu  = muA[(32 + q) * 64 + lane];
        nrm = nrmA[(32 + q) * 64 + lane];
    } else {
        // b-marginals: block per (w, q-group of 32), k enumerates qlocal
        int id = blockIdx.x - 256;
        int w = id >> 3, qg = id & 7;
        for (int t = threadIdx.x; t < 4096; t += 256) {
            int c = t >> 3, k = t & 7;
            ((float4*)WL)[t] = ((const float4*)(QpT + (size_t)c * 256 + qg * 32))[k];
        }
        if (threadIdx.x < 32) Sl[threadIdx.x] = Ssc[32 + qg * 32 + threadIdx.x]; // S'_q
        src16 = Vht + (size_t)w * 32768;
        mu  = muA[w * 64 + lane];
        nrm = nrmA[w * 64 + lane];
    }
    __syncthreads();

    // lane's node-n data: chunk (kk, t=n>>4, slot=(hi<<4)|(n&15)) = c kk*32+hi*8..+8
    int lbase = (lane >> 4) * 64 + (lane & 15);
    float acc[8] = {0, 0, 0, 0, 0, 0, 0, 0};
#pragma unroll 1
    for (int kk = 0; kk < 16; ++kk) {
#pragma unroll
        for (int hi = 0; hi < 4; ++hi) {
            half8 x8 = *(const half8*)(src16 +
                        ((size_t)(kk * 256 + lbase + (hi << 4)) * 8));
            int cb = kk * 32 + hi * 8;
#pragma unroll
            for (int j = 0; j < 8; ++j) {
                float xv = (float)x8[j];
                const float* wl = WL + (cb + j) * 32 + kq * 8;
                float4 b0 = *(const float4*)wl;
                float4 b1 = *(const float4*)(wl + 4);
                acc[0] = fmaf(xv, b0.x, acc[0]); acc[1] = fmaf(xv, b0.y, acc[1]);
                acc[2] = fmaf(xv, b0.z, acc[2]); acc[3] = fmaf(xv, b0.w, acc[3]);
                acc[4] = fmaf(xv, b1.x, acc[4]); acc[5] = fmaf(xv, b1.y, acc[5]);
                acc[6] = fmaf(xv, b1.z, acc[6]); acc[7] = fmaf(xv, b1.w, acc[7]);
            }
        }
    }
#pragma unroll
    for (int k = 0; k < 8; ++k) {
        float raw = fmaf(mu, Sl[kq * 8 + k], nrm * acc[k]);
        float v = fmaxf(raw, 0.0f) + 0.001f;
        v += 1e-5f;
        float s = v;
        s += __shfl_xor(s, 1);  s += __shfl_xor(s, 2);  s += __shfl_xor(s, 4);
        s += __shfl_xor(s, 8);  s += __shfl_xor(s, 16); s += __shfl_xor(s, 32);
        v = v * (64.0f / s);
        if (blockIdx.x < 256) {
            int q = (blockIdx.x & 7) * 32 + (blockIdx.x >> 3), w = kq * 8 + k;
            a_out[((size_t)q * 32 + w) * 64 + lane] = v;
        } else {
            int id = blockIdx.x - 256;
            int w = id >> 3, q = (id & 7) * 32 + kq * 8 + k;
            b_out[((size_t)w * 256 + q) * 64 + lane] = v;
        }
    }
}

// --------- K3: FUSED MFMA sim + exp/transpose + Sinkhorn + logits -----------
// Wave per (q,w). XCD-resident: blockIdx%8 = XCD handles one q-group.
// R13: M kept in f32 registers (Mf[8][8]) -- acc AGPRs are dead by phase 3
// so lifetimes overlap inside the 128-reg budget; removes the 128
// v_cvt_f32_f16 per Sinkhorn iteration that dominated VALUBusy.
__global__ void __launch_bounds__(256, 4)
emd_kernel(const _Float16* __restrict__ Uht, const _Float16* __restrict__ Vht,
           const float* __restrict__ a_arr, const float* __restrict__ b_arr,
           float* __restrict__ out) {
    __shared__ __align__(16) float T[2][64 * LDP];   // 34.8 KB

    int x    = blockIdx.x & 7;
    int i    = blockIdx.x >> 3;
    int w    = i & 31;
    int wave = threadIdx.x >> 6;
    int lane = threadIdx.x & 63;
    int q    = (x * 8 + (i >> 5)) * 4 + wave;        // XCD x: q in [32x,32x+32)
    int lo16 = lane & 15;
    int hi4  = lane >> 4;
    int ig   = lane >> 3;
    int jg   = lane & 7;

    // ---- phase 1: sim tile via fp16 MFMA, fragment-order loads ----
    floatx4 acc[4][4];
#pragma unroll
    for (int tm = 0; tm < 4; ++tm)
#pragma unroll
        for (int tn = 0; tn < 4; ++tn)
            acc[tm][tn] = (floatx4){0.f, 0.f, 0.f, 0.f};

    const _Float16* Abase = Uht + (size_t)q * 32768 + lane * 8;
    const _Float16* Bbase = Vht + (size_t)w * 32768 + lane * 8;
#pragma unroll 1
    for (int kk = 0; kk < 16; ++kk) {
        half8 bf[4];
#pragma unroll
        for (int t = 0; t < 4; ++t)
            bf[t] = *(const half8*)(Bbase + (size_t)(kk * 4 + t) * 512);
#pragma unroll
        for (int tm = 0; tm < 4; ++tm) {
            half8 af = *(const half8*)(Abase + (size_t)(kk * 4 + tm) * 512);
#pragma unroll
            for (int tn = 0; tn < 4; ++tn)
                acc[tm][tn] = __builtin_amdgcn_mfma_f32_16x16x32_f16(
                    af, bf[tn], acc[tm][tn], 0, 0, 0);
        }
    }

    // ---- wave-uniform tile max for the fp16 rescale ----
    float lmax = -2.0f;
#pragma unroll
    for (int tm = 0; tm < 4; ++tm)
#pragma unroll
        for (int tn = 0; tn < 4; ++tn)
#pragma unroll
            for (int r = 0; r < 4; ++r) lmax = fmaxf(lmax, acc[tm][tn][r]);
    lmax = fmaxf(lmax, __shfl_xor(lmax, 1));
    lmax = fmaxf(lmax, __shfl_xor(lmax, 2));
    lmax = fmaxf(lmax, __shfl_xor(lmax, 4));
    lmax = fmaxf(lmax, __shfl_xor(lmax, 8));
    lmax = fmaxf(lmax, __shfl_xor(lmax, 16));
    lmax = fmaxf(lmax, __shfl_xor(lmax, 32));
    float s0 = lmax;

    // ---- phase 2: exp + LDS roundtrip into xor-permuted layout, f32 regs ----
    float Mf[8][8];
#pragma unroll 1
    for (int round = 0; round < 2; ++round) {
        if ((wave >> 1) == round) {
            float* buf = T[wave & 1];
#pragma unroll
            for (int tm = 0; tm < 4; ++tm)
#pragma unroll
                for (int tn = 0; tn < 4; ++tn)
#pragma unroll
                    for (int r = 0; r < 4; ++r) {
                        int row = tm * 16 + hi4 * 4 + r;
                        int col = tn * 16 + lo16;
                        int sp  = (col & 7) ^ (row >> 3);
                        buf[row * LDP + (col & ~7) + sp] =
                            fexp2((acc[tm][tn][r] - s0) * K_SIM2M);
                    }
        }
        __syncthreads();
        if ((wave >> 1) == round) {
            const float* buf = T[wave & 1];
#pragma unroll
            for (int t = 0; t < 8; ++t) {
                const float* p = buf + (ig * 8 + (jg ^ t)) * LDP + jg * 8;
                float4 m0 = *(const float4*)p;
                float4 m1 = *(const float4*)(p + 4);
                Mf[t][0] = m0.x; Mf[t][1] = m0.y; Mf[t][2] = m0.z; Mf[t][3] = m0.w;
                Mf[t][4] = m1.x; Mf[t][5] = m1.y; Mf[t][6] = m1.z; Mf[t][7] = m1.w;
            }
        }
        __syncthreads();
    }

    // ---- phase 3: Sinkhorn, reduce-scatter + all-gather, tol early exit ----
    int gp = q * 32 + w;
    float a_own = a_arr[(size_t)gp * 64 + ig * 8 + jg];
    float b_own = b_arr[((size_t)w * 256 + q) * 64 + jg * 8 + ig];

    float wvp[8];
#pragma unroll
    for (int s = 0; s < 8; ++s) wvp[s] = 1.0f;
    float q8[8];
    float w_prev = -1.f;

#pragma unroll 1
    for (int it = 0; it < 100; ++it) {
        float p[8];
#pragma unroll
        for (int t = 0; t < 8; ++t) {
            float s = Mf[t][0] * wvp[0];
#pragma unroll
            for (int c = 1; c < 8; ++c) s = fmaf(Mf[t][c], wvp[c], s);
            p[t] = s;
        }
        p[0] += __shfl_xor(p[4], 4); p[1] += __shfl_xor(p[5], 4);
        p[2] += __shfl_xor(p[6], 4); p[3] += __shfl_xor(p[7], 4);
        p[0] += __shfl_xor(p[2], 2); p[1] += __shfl_xor(p[3], 2);
        p[0] += __shfl_xor(p[1], 1);
        float z_own = a_own * fast_rcp(p[0]);
        q8[0] = z_own;
        q8[1] = __shfl_xor(q8[0], 1);
        q8[2] = __shfl_xor(q8[0], 2); q8[3] = __shfl_xor(q8[1], 2);
        q8[4] = __shfl_xor(q8[0], 4); q8[5] = __shfl_xor(q8[1], 4);
        q8[6] = __shfl_xor(q8[2], 4); q8[7] = __shfl_xor(q8[3], 4);
        float cp[8];
#pragma unroll
        for (int s = 0; s < 8; ++s) {
            float v = Mf[0][s] * q8[0];
#pragma unroll
            for (int t = 1; t < 8; ++t) v = fmaf(Mf[t][s], q8[t], v);
            cp[s] = v;
        }
        cp[0] += __shfl_xor(cp[4], 32); cp[1] += __shfl_xor(cp[5], 32);
        cp[2] += __shfl_xor(cp[6], 32); cp[3] += __shfl_xor(cp[7], 32);
        cp[0] += __shfl_xor(cp[2], 16); cp[1] += __shfl_xor(cp[3], 16);
        cp[0] += __shfl_xor(cp[1], 8);
        float w_own = b_own * fast_rcp(cp[0]);
        wvp[0] = w_own;
        wvp[1] = __shfl_xor(wvp[0], 8);
        wvp[2] = __shfl_xor(wvp[0], 16); wvp[3] = __shfl_xor(wvp[1], 16);
        wvp[4] = __shfl_xor(wvp[0], 32); wvp[5] = __shfl_xor(wvp[1], 32);
        wvp[6] = __shfl_xor(wvp[2], 32); wvp[7] = __shfl_xor(wvp[3], 32);
        // w stable across all 64 cols -> next z,w identical -> fixed point
        bool same = fabsf(w_own - w_prev) <= 1e-5f * w_own;
        w_prev = w_own;
        if (__all(same)) break;
    }

    // ---- phase 4: logits; sim = s0 + log2(M')*eps*ln2 ----
    float s = 0.f;
#pragma unroll
    for (int t = 0; t < 8; ++t)
#pragma unroll
        for (int c = 0; c < 8; ++c) {
            float m    = fmaxf(Mf[t][c], 1e-30f);
            float sim  = fmaf(flog2(m), K_M2SIM, s0);
            float flow = q8[t] * m * wvp[c];
            s = fmaf(sim, flow, s);
        }
    s += __shfl_xor(s, 1);  s += __shfl_xor(s, 2);  s += __shfl_xor(s, 4);
    s += __shfl_xor(s, 8);  s += __shfl_xor(s, 16); s += __shfl_xor(s, 32);
    if (lane == 0) out[gp] = s * 0.1953125f;   // 12.5/64
}

// ---------------------------------------------------------------------------
extern "C" void kernel_launch(void* const* d_in, const int* in_sizes, int n_in,
                              void* d_out, int out_size, void* d_ws, size_t ws_size,
                              hipStream_t stream) {
    (void)in_sizes; (void)n_in; (void)out_size; (void)ws_size;
    const float* support = (const float*)d_in[0];   // 32*512*64
    const float* query   = (const float*)d_in[1];   // 256*512*64

    char* ws = (char*)d_ws;
    _Float16* Uht = (_Float16*)ws;                  // 16 MB (fragment order)
    _Float16* Vht = Uht + 8388608;                  //  2 MB (fragment order)
    float* BpT  = (float*)(Vht + 1048576);          // 64 KB  [512][32]
    float* QpT  = BpT + 16384;                      // 512 KB [512][256]
    float* aA   = QpT + 131072;                     //  2 MB
    float* bA   = aA + 524288;                      //  2 MB
    float* muA  = bA + 524288;                      // 72 KB [288][64]
    float* nrmA = muA + 18432;                      // 72 KB
    float* Ssc  = nrmA + 18432;                     // ~1 KB [288]  (~23 MB total)

    norm_kernel<<<288, 1024, 0, stream>>>(support, query, Vht, Uht, BpT, QpT,
                                          muA, nrmA, Ssc);
    marg_kernel<<<512, 256, 0, stream>>>(Uht, Vht, BpT, QpT, muA, nrmA, Ssc,
                                         aA, bA);
    emd_kernel<<<2048, 256, 0, stream>>>(Uht, Vht, aA, bA, (float*)d_out);
}

// Round 3
// 183.527 us; speedup vs baseline: 3.5151x; 1.1435x over previous
//
#include <hip/hip_runtime.h>
#include <math.h>

// ---------------------------------------------------------------------------
// EMD layer (Sinkhorn-OT logits) for MI355X.
// support: [32,512,8,8] f32, query: [256,512,8,8] f32 -> logits [256,32] f32.
//
// R14: f32-M Sinkhorn WITHOUT the R13 spill. R13's FETCH 18->54MB / WRITE
//      0->57MB showed Mf spilled: the phase-2 ROUND loop kept acc[4][4]
//      (64 AGPR) statically live across the round where Mf (64 f32) is
//      born -> 64+64+working > 128-reg budget. Fix: per-wave f16 LDS
//      buffers (4 x 64x72 halves = 36.9KB < 40KB @ 4 blocks/CU) so phase 2
//      is linear: all waves write f16 exp -> 1 barrier -> all waves read
//      Mf. acc dies before Mf is born -> disjoint ranges, no spill.
//      Numerics bit-identical to R11 (same f16 rounding point: f32 exp ->
//      f16 -> f32 once, instead of f32 LDS -> f16 Mh -> f32 per use).
//      Removes the 128 v_cvt_f32_f16 per Sinkhorn iteration (~286 -> ~158
//      VALU ops/iter). norm/marg unchanged.
// ---------------------------------------------------------------------------

#define DEV static __device__ __forceinline__

typedef _Float16 half8 __attribute__((ext_vector_type(8)));
typedef float floatx4 __attribute__((ext_vector_type(4)));

DEV float fast_rcp(float x) {
#if __has_builtin(__builtin_amdgcn_rcpf)
    return __builtin_amdgcn_rcpf(x);
#else
    return 1.0f / x;
#endif
}
DEV float fexp2(float x) {
#if __has_builtin(__builtin_amdgcn_exp2f)
    return __builtin_amdgcn_exp2f(x);
#else
    return exp2f(x);
#endif
}
DEV float flog2(float x) {
#if __has_builtin(__builtin_amdgcn_logf)
    return __builtin_amdgcn_logf(x);
#else
    return log2f(x);
#endif
}

#define K_SIM2M 28.853900817779268f    // 20/ln2 : M = 2^((sim-1)*K_SIM2M)
#define K_M2SIM 0.034657359027997264f  // 0.05*ln2 : sim = 1 + log2(M)*K_M2SIM
#define LDP 68                         // padded LDS row stride (floats, norm)
#define LDPH 72                        // padded LDS row stride (halves, emd)

// ------ K1: center+normalize over C -> fp16 FRAGMENT order, + pool stats ----
// 1024 threads: 16 waves. Fragment chunk (kk,t,slot) = channels
// kk*32+(slot>>4)*8..+8 of node t*16+(slot&15), at ((kk*4+t)*64+slot)*8 halves.
__global__ void __launch_bounds__(1024, 1)
norm_kernel(const float* __restrict__ support, const float* __restrict__ query,
            _Float16* __restrict__ Vht, _Float16* __restrict__ Uht,
            float* __restrict__ BpT, float* __restrict__ QpT,
            float* __restrict__ muA, float* __restrict__ nrmA,
            float* __restrict__ Ssc) {
    __shared__ float red1[16][64];
    __shared__ float red2[16][64];
    __shared__ float muL[64], invL[64];
    __shared__ float tile[128][65];

    int sid = blockIdx.x;             // 0..287
    const float* src;
    _Float16* dst;
    float* poolT;
    int pstride, pidx;
    if (sid < 32) {
        src = support + (size_t)sid * 32768; dst = Vht + (size_t)sid * 32768;
        poolT = BpT; pstride = 32; pidx = sid;
    } else {
        src = query + (size_t)(sid - 32) * 32768; dst = Uht + (size_t)(sid - 32) * 32768;
        poolT = QpT; pstride = 256; pidx = sid - 32;
    }

    int node = threadIdx.x & 63;
    int cq   = threadIdx.x >> 6;      // wave index 0..15

    // ---- stats pass: each wave handles 32 channels ----
    float s1 = 0.f, s2 = 0.f;
#pragma unroll 8
    for (int j = 0; j < 32; ++j) {
        int c = cq * 32 + j;
        float x = src[c * 64 + node];
        s1 += x; s2 += x * x;
        float ps = x;                  // pool: sum over the wave's 64 nodes
        ps += __shfl_xor(ps, 1);  ps += __shfl_xor(ps, 2);  ps += __shfl_xor(ps, 4);
        ps += __shfl_xor(ps, 8);  ps += __shfl_xor(ps, 16); ps += __shfl_xor(ps, 32);
        if (node == 0) poolT[(size_t)c * pstride + pidx] = ps * (1.0f / 64.0f);
    }
    red1[cq][node] = s1;
    red2[cq][node] = s2;
    __syncthreads();
    if (threadIdx.x < 64) {
        float t1 = 0.f, t2 = 0.f;
#pragma unroll
        for (int k = 0; k < 16; ++k) { t1 += red1[k][node]; t2 += red2[k][node]; }
        float mu  = t1 * (1.0f / 512.0f);
        float ss  = t2 - 512.0f * mu * mu;
        float nrm = fmaxf(sqrtf(fmaxf(ss, 0.0f)), 1e-8f);
        muL[node]  = mu;
        invL[node] = 1.0f / nrm;
        muA[sid * 64 + node]  = mu;
        nrmA[sid * 64 + node] = nrm;
        float sS = t1;                 // S = sum_c pool[c]
        sS += __shfl_xor(sS, 1);  sS += __shfl_xor(sS, 2);  sS += __shfl_xor(sS, 4);
        sS += __shfl_xor(sS, 8);  sS += __shfl_xor(sS, 16); sS += __shfl_xor(sS, 32);
        if (node == 0) Ssc[sid] = sS * (1.0f / 64.0f);
    }
    __syncthreads();

    // ---- normalize + fragment-order write, slab = 128 channels ----
    float mu = muL[node], inv = invL[node];
    for (int ch = 0; ch < 4; ++ch) {
#pragma unroll
        for (int j = 0; j < 8; ++j) {
            int cl = cq * 8 + j;       // 16 waves x 8 = 128 channels
            float x = src[(ch * 128 + cl) * 64 + node];
            tile[cl][node] = (x - mu) * inv;
        }
        __syncthreads();
        // 1024 fragment chunks per slab: exactly one per thread
        {
            int g    = threadIdx.x;    // kkl*256 + t*64 + slot
            int slot = g & 63;
            int t    = (g >> 6) & 3;
            int kkl  = g >> 8;
            int nd   = t * 16 + (slot & 15);
            int c8   = (kkl << 2) | (slot >> 4);
            half8 v;
#pragma unroll
            for (int i = 0; i < 8; ++i) v[i] = (_Float16)tile[c8 * 8 + i][nd];
            *(half8*)(dst + ((size_t)ch * 1024 + g) * 8) = v;
        }
        __syncthreads();
    }
}

// --------- K2: merged a/b marginals from fragment-order fp16 ----------------
// raw_dot = nrm * <fp16 normalized vec, pooled vec> + mu * S(pooled vec)
__global__ void __launch_bounds__(256)
marg_kernel(const _Float16* __restrict__ Uht, const _Float16* __restrict__ Vht,
            const float* __restrict__ BpT, const float* __restrict__ QpT,
            const float* __restrict__ muA, const float* __restrict__ nrmA,
            const float* __restrict__ Ssc,
            float* __restrict__ a_out, float* __restrict__ b_out) {
    __shared__ __align__(16) float WL[512 * 32];   // [c][k] 64 KB
    __shared__ float Sl[32];
    int lane = threadIdx.x & 63;   // node
    int kq   = threadIdx.x >> 6;   // k = kq*8 .. +7

    const _Float16* src16;
    float mu, nrm;
    if (blockIdx.x < 256) {
        // a-marginals: block per q (XCD-grouped), k enumerates w (32)
        int q = (blockIdx.x & 7) * 32 + (blockIdx.x >> 3);
        for (int t = threadIdx.x; t < 4096; t += 256)
            ((float4*)WL)[t] = ((const float4*)BpT)[t];
        if (threadIdx.x < 32) Sl[threadIdx.x] = Ssc[threadIdx.x];  // S_w
        src16 = Uht + (size_t)q * 32768;
        mu  = muA[(32 + q) * 64 + lane];
        nrm = nrmA[(32 + q) * 64 + lane];
    } else {
        // b-marginals: block per (w, q-group of 32), k enumerates qlocal
        int id = blockIdx.x - 256;
        int w = id >> 3, qg = id & 7;
        for (int t = threadIdx.x; t < 4096; t += 256) {
            int c = t >> 3, k = t & 7;
            ((float4*)WL)[t] = ((const float4*)(QpT + (size_t)c * 256 + qg * 32))[k];
        }
        if (threadIdx.x < 32) Sl[threadIdx.x] = Ssc[32 + qg * 32 + threadIdx.x]; // S'_q
        src16 = Vht + (size_t)w * 32768;
        mu  = muA[w * 64 + lane];
        nrm = nrmA[w * 64 + lane];
    }
    __syncthreads();

    // lane's node-n data: chunk (kk, t=n>>4, slot=(hi<<4)|(n&15)) = c kk*32+hi*8..+8
    int lbase = (lane >> 4) * 64 + (lane & 15);
    float acc[8] = {0, 0, 0, 0, 0, 0, 0, 0};
#pragma unroll 1
    for (int kk = 0; kk < 16; ++kk) {
#pragma unroll
        for (int hi = 0; hi < 4; ++hi) {
            half8 x8 = *(const half8*)(src16 +
                        ((size_t)(kk * 256 + lbase + (hi << 4)) * 8));
            int cb = kk * 32 + hi * 8;
#pragma unroll
            for (int j = 0; j < 8; ++j) {
                float xv = (float)x8[j];
                const float* wl = WL + (cb + j) * 32 + kq * 8;
                float4 b0 = *(const float4*)wl;
                float4 b1 = *(const float4*)(wl + 4);
                acc[0] = fmaf(xv, b0.x, acc[0]); acc[1] = fmaf(xv, b0.y, acc[1]);
                acc[2] = fmaf(xv, b0.z, acc[2]); acc[3] = fmaf(xv, b0.w, acc[3]);
                acc[4] = fmaf(xv, b1.x, acc[4]); acc[5] = fmaf(xv, b1.y, acc[5]);
                acc[6] = fmaf(xv, b1.z, acc[6]); acc[7] = fmaf(xv, b1.w, acc[7]);
            }
        }
    }
#pragma unroll
    for (int k = 0; k < 8; ++k) {
        float raw = fmaf(mu, Sl[kq * 8 + k], nrm * acc[k]);
        float v = fmaxf(raw, 0.0f) + 0.001f;
        v += 1e-5f;
        float s = v;
        s += __shfl_xor(s, 1);  s += __shfl_xor(s, 2);  s += __shfl_xor(s, 4);
        s += __shfl_xor(s, 8);  s += __shfl_xor(s, 16); s += __shfl_xor(s, 32);
        v = v * (64.0f / s);
        if (blockIdx.x < 256) {
            int q = (blockIdx.x & 7) * 32 + (blockIdx.x >> 3), w = kq * 8 + k;
            a_out[((size_t)q * 32 + w) * 64 + lane] = v;
        } else {
            int id = blockIdx.x - 256;
            int w = id >> 3, q = (id & 7) * 32 + kq * 8 + k;
            b_out[((size_t)w * 256 + q) * 64 + lane] = v;
        }
    }
}

// --------- K3: FUSED MFMA sim + exp/transpose + Sinkhorn + logits -----------
// Wave per (q,w). XCD-resident: blockIdx%8 = XCD handles one q-group.
// R14: per-wave f16 LDS transpose buffer -> linear phase 2 (write / barrier /
// read), acc dead before Mf born -> f32 M in regs with NO spill. Sinkhorn
// math identical to R11 (same f16 rounding point), minus 128 cvt/iter.
__global__ void __launch_bounds__(256, 4)
emd_kernel(const _Float16* __restrict__ Uht, const _Float16* __restrict__ Vht,
           const float* __restrict__ a_arr, const float* __restrict__ b_arr,
           float* __restrict__ out) {
    __shared__ __align__(16) _Float16 T[4][64 * LDPH];   // 36,864 B

    int x    = blockIdx.x & 7;
    int i    = blockIdx.x >> 3;
    int w    = i & 31;
    int wave = threadIdx.x >> 6;
    int lane = threadIdx.x & 63;
    int q    = (x * 8 + (i >> 5)) * 4 + wave;        // XCD x: q in [32x,32x+32)
    int lo16 = lane & 15;
    int hi4  = lane >> 4;
    int ig   = lane >> 3;
    int jg   = lane & 7;

    // ---- phase 1: sim tile via fp16 MFMA, fragment-order loads ----
    floatx4 acc[4][4];
#pragma unroll
    for (int tm = 0; tm < 4; ++tm)
#pragma unroll
        for (int tn = 0; tn < 4; ++tn)
            acc[tm][tn] = (floatx4){0.f, 0.f, 0.f, 0.f};

    const _Float16* Abase = Uht + (size_t)q * 32768 + lane * 8;
    const _Float16* Bbase = Vht + (size_t)w * 32768 + lane * 8;
#pragma unroll 1
    for (int kk = 0; kk < 16; ++kk) {
        half8 bf[4];
#pragma unroll
        for (int t = 0; t < 4; ++t)
            bf[t] = *(const half8*)(Bbase + (size_t)(kk * 4 + t) * 512);
#pragma unroll
        for (int tm = 0; tm < 4; ++tm) {
            half8 af = *(const half8*)(Abase + (size_t)(kk * 4 + tm) * 512);
#pragma unroll
            for (int tn = 0; tn < 4; ++tn)
                acc[tm][tn] = __builtin_amdgcn_mfma_f32_16x16x32_f16(
                    af, bf[tn], acc[tm][tn], 0, 0, 0);
        }
    }

    // ---- wave-uniform tile max for the fp16 rescale ----
    float lmax = -2.0f;
#pragma unroll
    for (int tm = 0; tm < 4; ++tm)
#pragma unroll
        for (int tn = 0; tn < 4; ++tn)
#pragma unroll
            for (int r = 0; r < 4; ++r) lmax = fmaxf(lmax, acc[tm][tn][r]);
    lmax = fmaxf(lmax, __shfl_xor(lmax, 1));
    lmax = fmaxf(lmax, __shfl_xor(lmax, 2));
    lmax = fmaxf(lmax, __shfl_xor(lmax, 4));
    lmax = fmaxf(lmax, __shfl_xor(lmax, 8));
    lmax = fmaxf(lmax, __shfl_xor(lmax, 16));
    lmax = fmaxf(lmax, __shfl_xor(lmax, 32));
    float s0 = lmax;

    // ---- phase 2: exp -> f16 LDS (per-wave buffer) -> f32 Mf regs ----
    // Same value path as R11: fexp2 result rounded to f16 once, then used
    // as f32 in all Sinkhorn math. acc is dead after the write block.
    {
        _Float16* buf = T[wave];
#pragma unroll
        for (int tm = 0; tm < 4; ++tm)
#pragma unroll
            for (int tn = 0; tn < 4; ++tn)
#pragma unroll
                for (int r = 0; r < 4; ++r) {
                    int row = tm * 16 + hi4 * 4 + r;
                    int col = tn * 16 + lo16;
                    int sp  = (col & 7) ^ (row >> 3);
                    buf[row * LDPH + (col & ~7) + sp] =
                        (_Float16)fexp2((acc[tm][tn][r] - s0) * K_SIM2M);
                }
    }
    __syncthreads();
    float Mf[8][8];
    {
        const _Float16* buf = T[wave];
#pragma unroll
        for (int t = 0; t < 8; ++t) {
            half8 h = *(const half8*)(buf + (ig * 8 + (jg ^ t)) * LDPH + jg * 8);
#pragma unroll
            for (int c = 0; c < 8; ++c) Mf[t][c] = (float)h[c];
        }
    }

    // ---- phase 3: Sinkhorn, reduce-scatter + all-gather, tol early exit ----
    int gp = q * 32 + w;
    float a_own = a_arr[(size_t)gp * 64 + ig * 8 + jg];
    float b_own = b_arr[((size_t)w * 256 + q) * 64 + jg * 8 + ig];

    float wvp[8];
#pragma unroll
    for (int s = 0; s < 8; ++s) wvp[s] = 1.0f;
    float q8[8];
    float w_prev = -1.f;

#pragma unroll 1
    for (int it = 0; it < 100; ++it) {
        float p[8];
#pragma unroll
        for (int t = 0; t < 8; ++t) {
            float s = Mf[t][0] * wvp[0];
#pragma unroll
            for (int c = 1; c < 8; ++c) s = fmaf(Mf[t][c], wvp[c], s);
            p[t] = s;
        }
        p[0] += __shfl_xor(p[4], 4); p[1] += __shfl_xor(p[5], 4);
        p[2] += __shfl_xor(p[6], 4); p[3] += __shfl_xor(p[7], 4);
        p[0] += __shfl_xor(p[2], 2); p[1] += __shfl_xor(p[3], 2);
        p[0] += __shfl_xor(p[1], 1);
        float z_own = a_own * fast_rcp(p[0]);
        q8[0] = z_own;
        q8[1] = __shfl_xor(q8[0], 1);
        q8[2] = __shfl_xor(q8[0], 2); q8[3] = __shfl_xor(q8[1], 2);
        q8[4] = __shfl_xor(q8[0], 4); q8[5] = __shfl_xor(q8[1], 4);
        q8[6] = __shfl_xor(q8[2], 4); q8[7] = __shfl_xor(q8[3], 4);
        float cp[8];
#pragma unroll
        for (int s = 0; s < 8; ++s) {
            float v = Mf[0][s] * q8[0];
#pragma unroll
            for (int t = 1; t < 8; ++t) v = fmaf(Mf[t][s], q8[t], v);
            cp[s] = v;
        }
        cp[0] += __shfl_xor(cp[4], 32); cp[1] += __shfl_xor(cp[5], 32);
        cp[2] += __shfl_xor(cp[6], 32); cp[3] += __shfl_xor(cp[7], 32);
        cp[0] += __shfl_xor(cp[2], 16); cp[1] += __shfl_xor(cp[3], 16);
        cp[0] += __shfl_xor(cp[1], 8);
        float w_own = b_own * fast_rcp(cp[0]);
        wvp[0] = w_own;
        wvp[1] = __shfl_xor(wvp[0], 8);
        wvp[2] = __shfl_xor(wvp[0], 16); wvp[3] = __shfl_xor(wvp[1], 16);
        wvp[4] = __shfl_xor(wvp[0], 32); wvp[5] = __shfl_xor(wvp[1], 32);
        wvp[6] = __shfl_xor(wvp[2], 32); wvp[7] = __shfl_xor(wvp[3], 32);
        // w stable across all 64 cols -> next z,w identical -> fixed point
        bool same = fabsf(w_own - w_prev) <= 1e-5f * w_own;
        w_prev = w_own;
        if (__all(same)) break;
    }

    // ---- phase 4: logits; sim = s0 + log2(M')*eps*ln2 ----
    float s = 0.f;
#pragma unroll
    for (int t = 0; t < 8; ++t)
#pragma unroll
        for (int c = 0; c < 8; ++c) {
            float m    = fmaxf(Mf[t][c], 1e-30f);
            float sim  = fmaf(flog2(m), K_M2SIM, s0);
            float flow = q8[t] * m * wvp[c];
            s = fmaf(sim, flow, s);
        }
    s += __shfl_xor(s, 1);  s += __shfl_xor(s, 2);  s += __shfl_xor(s, 4);
    s += __shfl_xor(s, 8);  s += __shfl_xor(s, 16); s += __shfl_xor(s, 32);
    if (lane == 0) out[gp] = s * 0.1953125f;   // 12.5/64
}

// ---------------------------------------------------------------------------
extern "C" void kernel_launch(void* const* d_in, const int* in_sizes, int n_in,
                              void* d_out, int out_size, void* d_ws, size_t ws_size,
                              hipStream_t stream) {
    (void)in_sizes; (void)n_in; (void)out_size; (void)ws_size;
    const float* support = (const float*)d_in[0];   // 32*512*64
    const float* query   = (const float*)d_in[1];   // 256*512*64

    char* ws = (char*)d_ws;
    _Float16* Uht = (_Float16*)ws;                  // 16 MB (fragment order)
    _Float16* Vht = Uht + 8388608;                  //  2 MB (fragment order)
    float* BpT  = (float*)(Vht + 1048576);          // 64 KB  [512][32]
    float* QpT  = BpT + 16384;                      // 512 KB [512][256]
    float* aA   = QpT + 131072;                     //  2 MB
    float* bA   = aA + 524288;                      //  2 MB
    float* muA  = bA + 524288;                      // 72 KB [288][64]
    float* nrmA = muA + 18432;                      // 72 KB
    float* Ssc  = nrmA + 18432;                     // ~1 KB [288]  (~23 MB total)

    norm_kernel<<<288, 1024, 0, stream>>>(support, query, Vht, Uht, BpT, QpT,
                                          muA, nrmA, Ssc);
    marg_kernel<<<512, 256, 0, stream>>>(Uht, Vht, BpT, QpT, muA, nrmA, Ssc,
                                         aA, bA);
    emd_kernel<<<2048, 256, 0, stream>>>(Uht, Vht, aA, bA, (float*)d_out);
}

// Round 4
// 183.247 us; speedup vs baseline: 3.5204x; 1.0015x over previous
//
#include <hip/hip_runtime.h>
#include <math.h>

// ---------------------------------------------------------------------------
// EMD layer (Sinkhorn-OT logits) for MI355X.
// support: [32,512,8,8] f32, query: [256,512,8,8] f32 -> logits [256,32] f32.
//
// R15: marg de-LDS'd. R14's marg issued 1024 ds_read_b128/thread of
//      WAVE-UNIFORM weight addresses through the LDS pipe (~8192 DS
//      instr/CU ~= 41us serialization) and its 64KB WL copy capped
//      occupancy at 2 blocks/CU. Weights are read-only global with a
//      wave-uniform address -> read them directly from BpT/QpT with a
//      readfirstlane-uniform base so they select the scalar (SMEM) path
//      (worst case: VMEM broadcast, still off the LDS pipe). WL/Sl LDS
//      staging deleted, no barriers, LDS=0. Same values, same fma order
//      -> bit-identical outputs. norm/emd = R14 unchanged (R14 emd:
//      f32-M, per-wave f16 LDS transpose, no spill).
// ---------------------------------------------------------------------------

#define DEV static __device__ __forceinline__

typedef _Float16 half8 __attribute__((ext_vector_type(8)));
typedef float floatx4 __attribute__((ext_vector_type(4)));

DEV float fast_rcp(float x) {
#if __has_builtin(__builtin_amdgcn_rcpf)
    return __builtin_amdgcn_rcpf(x);
#else
    return 1.0f / x;
#endif
}
DEV float fexp2(float x) {
#if __has_builtin(__builtin_amdgcn_exp2f)
    return __builtin_amdgcn_exp2f(x);
#else
    return exp2f(x);
#endif
}
DEV float flog2(float x) {
#if __has_builtin(__builtin_amdgcn_logf)
    return __builtin_amdgcn_logf(x);
#else
    return log2f(x);
#endif
}

#define K_SIM2M 28.853900817779268f    // 20/ln2 : M = 2^((sim-1)*K_SIM2M)
#define K_M2SIM 0.034657359027997264f  // 0.05*ln2 : sim = 1 + log2(M)*K_M2SIM
#define LDPH 72                        // padded LDS row stride (halves, emd)

// ------ K1: center+normalize over C -> fp16 FRAGMENT order, + pool stats ----
// 1024 threads: 16 waves. Fragment chunk (kk,t,slot) = channels
// kk*32+(slot>>4)*8..+8 of node t*16+(slot&15), at ((kk*4+t)*64+slot)*8 halves.
__global__ void __launch_bounds__(1024, 1)
norm_kernel(const float* __restrict__ support, const float* __restrict__ query,
            _Float16* __restrict__ Vht, _Float16* __restrict__ Uht,
            float* __restrict__ BpT, float* __restrict__ QpT,
            float* __restrict__ muA, float* __restrict__ nrmA,
            float* __restrict__ Ssc) {
    __shared__ float red1[16][64];
    __shared__ float red2[16][64];
    __shared__ float muL[64], invL[64];
    __shared__ float tile[128][65];

    int sid = blockIdx.x;             // 0..287
    const float* src;
    _Float16* dst;
    float* poolT;
    int pstride, pidx;
    if (sid < 32) {
        src = support + (size_t)sid * 32768; dst = Vht + (size_t)sid * 32768;
        poolT = BpT; pstride = 32; pidx = sid;
    } else {
        src = query + (size_t)(sid - 32) * 32768; dst = Uht + (size_t)(sid - 32) * 32768;
        poolT = QpT; pstride = 256; pidx = sid - 32;
    }

    int node = threadIdx.x & 63;
    int cq   = threadIdx.x >> 6;      // wave index 0..15

    // ---- stats pass: each wave handles 32 channels ----
    float s1 = 0.f, s2 = 0.f;
#pragma unroll 8
    for (int j = 0; j < 32; ++j) {
        int c = cq * 32 + j;
        float x = src[c * 64 + node];
        s1 += x; s2 += x * x;
        float ps = x;                  // pool: sum over the wave's 64 nodes
        ps += __shfl_xor(ps, 1);  ps += __shfl_xor(ps, 2);  ps += __shfl_xor(ps, 4);
        ps += __shfl_xor(ps, 8);  ps += __shfl_xor(ps, 16); ps += __shfl_xor(ps, 32);
        if (node == 0) poolT[(size_t)c * pstride + pidx] = ps * (1.0f / 64.0f);
    }
    red1[cq][node] = s1;
    red2[cq][node] = s2;
    __syncthreads();
    if (threadIdx.x < 64) {
        float t1 = 0.f, t2 = 0.f;
#pragma unroll
        for (int k = 0; k < 16; ++k) { t1 += red1[k][node]; t2 += red2[k][node]; }
        float mu  = t1 * (1.0f / 512.0f);
        float ss  = t2 - 512.0f * mu * mu;
        float nrm = fmaxf(sqrtf(fmaxf(ss, 0.0f)), 1e-8f);
        muL[node]  = mu;
        invL[node] = 1.0f / nrm;
        muA[sid * 64 + node]  = mu;
        nrmA[sid * 64 + node] = nrm;
        float sS = t1;                 // S = sum_c pool[c]
        sS += __shfl_xor(sS, 1);  sS += __shfl_xor(sS, 2);  sS += __shfl_xor(sS, 4);
        sS += __shfl_xor(sS, 8);  sS += __shfl_xor(sS, 16); sS += __shfl_xor(sS, 32);
        if (node == 0) Ssc[sid] = sS * (1.0f / 64.0f);
    }
    __syncthreads();

    // ---- normalize + fragment-order write, slab = 128 channels ----
    float mu = muL[node], inv = invL[node];
    for (int ch = 0; ch < 4; ++ch) {
#pragma unroll
        for (int j = 0; j < 8; ++j) {
            int cl = cq * 8 + j;       // 16 waves x 8 = 128 channels
            float x = src[(ch * 128 + cl) * 64 + node];
            tile[cl][node] = (x - mu) * inv;
        }
        __syncthreads();
        // 1024 fragment chunks per slab: exactly one per thread
        {
            int g    = threadIdx.x;    // kkl*256 + t*64 + slot
            int slot = g & 63;
            int t    = (g >> 6) & 3;
            int kkl  = g >> 8;
            int nd   = t * 16 + (slot & 15);
            int c8   = (kkl << 2) | (slot >> 4);
            half8 v;
#pragma unroll
            for (int i = 0; i < 8; ++i) v[i] = (_Float16)tile[c8 * 8 + i][nd];
            *(half8*)(dst + ((size_t)ch * 1024 + g) * 8) = v;
        }
        __syncthreads();
    }
}

// --------- K2: merged a/b marginals, weights via wave-uniform loads ---------
// raw_dot = nrm * <fp16 normalized vec, pooled vec> + mu * S(pooled vec)
template <int WS>
DEV void marg_loop(const _Float16* __restrict__ src16,
                   const float* __restrict__ wbase,
                   int lbase, float acc[8]) {
#pragma unroll 1
    for (int kk = 0; kk < 16; ++kk) {
#pragma unroll
        for (int hi = 0; hi < 4; ++hi) {
            half8 x8 = *(const half8*)(src16 +
                        ((size_t)(kk * 256 + lbase + (hi << 4)) * 8));
            int cb = kk * 32 + hi * 8;
#pragma unroll
            for (int j = 0; j < 8; ++j) {
                float xv = (float)x8[j];
                const float* wl = wbase + (size_t)(cb + j) * WS;
                float4 b0 = *(const float4*)wl;
                float4 b1 = *(const float4*)(wl + 4);
                acc[0] = fmaf(xv, b0.x, acc[0]); acc[1] = fmaf(xv, b0.y, acc[1]);
                acc[2] = fmaf(xv, b0.z, acc[2]); acc[3] = fmaf(xv, b0.w, acc[3]);
                acc[4] = fmaf(xv, b1.x, acc[4]); acc[5] = fmaf(xv, b1.y, acc[5]);
                acc[6] = fmaf(xv, b1.z, acc[6]); acc[7] = fmaf(xv, b1.w, acc[7]);
            }
        }
    }
}

__global__ void __launch_bounds__(256)
marg_kernel(const _Float16* __restrict__ Uht, const _Float16* __restrict__ Vht,
            const float* __restrict__ BpT, const float* __restrict__ QpT,
            const float* __restrict__ muA, const float* __restrict__ nrmA,
            const float* __restrict__ Ssc,
            float* __restrict__ a_out, float* __restrict__ b_out) {
    int lane = threadIdx.x & 63;   // node
    int kq   = threadIdx.x >> 6;   // k = kq*8 .. +7  (wave index, uniform)
    int kqu  = __builtin_amdgcn_readfirstlane(kq);

    const _Float16* src16;
    const float* wbase;            // wave-uniform weight base
    const float* sbase;            // wave-uniform Ssc base
    float mu, nrm;
    if (blockIdx.x < 256) {
        // a-marginals: block per q (XCD-grouped), k enumerates w (32)
        int q = (blockIdx.x & 7) * 32 + (blockIdx.x >> 3);
        src16 = Uht + (size_t)q * 32768;
        wbase = BpT + kqu * 8;                 // stride 32 per channel
        sbase = Ssc + kqu * 8;                 // S_w
        mu  = muA[(32 + q) * 64 + lane];
        nrm = nrmA[(32 + q) * 64 + lane];
    } else {
        // b-marginals: block per (w, q-group of 32), k enumerates qlocal
        int id = blockIdx.x - 256;
        int w = id >> 3, qg = id & 7;
        src16 = Vht + (size_t)w * 32768;
        wbase = QpT + qg * 32 + kqu * 8;       // stride 256 per channel
        sbase = Ssc + 32 + qg * 32 + kqu * 8;  // S'_q
        mu  = muA[w * 64 + lane];
        nrm = nrmA[w * 64 + lane];
    }

    // lane's node-n data: chunk (kk, t=n>>4, slot=(hi<<4)|(n&15)) = c kk*32+hi*8..+8
    int lbase = (lane >> 4) * 64 + (lane & 15);
    float acc[8] = {0, 0, 0, 0, 0, 0, 0, 0};
    if (blockIdx.x < 256) marg_loop<32>(src16, wbase, lbase, acc);
    else                  marg_loop<256>(src16, wbase, lbase, acc);

#pragma unroll
    for (int k = 0; k < 8; ++k) {
        float raw = fmaf(mu, sbase[k], nrm * acc[k]);
        float v = fmaxf(raw, 0.0f) + 0.001f;
        v += 1e-5f;
        float s = v;
        s += __shfl_xor(s, 1);  s += __shfl_xor(s, 2);  s += __shfl_xor(s, 4);
        s += __shfl_xor(s, 8);  s += __shfl_xor(s, 16); s += __shfl_xor(s, 32);
        v = v * (64.0f / s);
        if (blockIdx.x < 256) {
            int q = (blockIdx.x & 7) * 32 + (blockIdx.x >> 3), w = kq * 8 + k;
            a_out[((size_t)q * 32 + w) * 64 + lane] = v;
        } else {
            int id = blockIdx.x - 256;
            int w = id >> 3, q = (id & 7) * 32 + kq * 8 + k;
            b_out[((size_t)w * 256 + q) * 64 + lane] = v;
        }
    }
}

// --------- K3: FUSED MFMA sim + exp/transpose + Sinkhorn + logits -----------
// Wave per (q,w). XCD-resident: blockIdx%8 = XCD handles one q-group.
// R14: per-wave f16 LDS transpose buffer -> linear phase 2 (write / barrier /
// read), acc dead before Mf born -> f32 M in regs with NO spill. Sinkhorn
// math identical to R11 (same f16 rounding point), minus 128 cvt/iter.
__global__ void __launch_bounds__(256, 4)
emd_kernel(const _Float16* __restrict__ Uht, const _Float16* __restrict__ Vht,
           const float* __restrict__ a_arr, const float* __restrict__ b_arr,
           float* __restrict__ out) {
    __shared__ __align__(16) _Float16 T[4][64 * LDPH];   // 36,864 B

    int x    = blockIdx.x & 7;
    int i    = blockIdx.x >> 3;
    int w    = i & 31;
    int wave = threadIdx.x >> 6;
    int lane = threadIdx.x & 63;
    int q    = (x * 8 + (i >> 5)) * 4 + wave;        // XCD x: q in [32x,32x+32)
    int lo16 = lane & 15;
    int hi4  = lane >> 4;
    int ig   = lane >> 3;
    int jg   = lane & 7;

    // ---- phase 1: sim tile via fp16 MFMA, fragment-order loads ----
    floatx4 acc[4][4];
#pragma unroll
    for (int tm = 0; tm < 4; ++tm)
#pragma unroll
        for (int tn = 0; tn < 4; ++tn)
            acc[tm][tn] = (floatx4){0.f, 0.f, 0.f, 0.f};

    const _Float16* Abase = Uht + (size_t)q * 32768 + lane * 8;
    const _Float16* Bbase = Vht + (size_t)w * 32768 + lane * 8;
#pragma unroll 1
    for (int kk = 0; kk < 16; ++kk) {
        half8 bf[4];
#pragma unroll
        for (int t = 0; t < 4; ++t)
            bf[t] = *(const half8*)(Bbase + (size_t)(kk * 4 + t) * 512);
#pragma unroll
        for (int tm = 0; tm < 4; ++tm) {
            half8 af = *(const half8*)(Abase + (size_t)(kk * 4 + tm) * 512);
#pragma unroll
            for (int tn = 0; tn < 4; ++tn)
                acc[tm][tn] = __builtin_amdgcn_mfma_f32_16x16x32_f16(
                    af, bf[tn], acc[tm][tn], 0, 0, 0);
        }
    }

    // ---- wave-uniform tile max for the fp16 rescale ----
    float lmax = -2.0f;
#pragma unroll
    for (int tm = 0; tm < 4; ++tm)
#pragma unroll
        for (int tn = 0; tn < 4; ++tn)
#pragma unroll
            for (int r = 0; r < 4; ++r) lmax = fmaxf(lmax, acc[tm][tn][r]);
    lmax = fmaxf(lmax, __shfl_xor(lmax, 1));
    lmax = fmaxf(lmax, __shfl_xor(lmax, 2));
    lmax = fmaxf(lmax, __shfl_xor(lmax, 4));
    lmax = fmaxf(lmax, __shfl_xor(lmax, 8));
    lmax = fmaxf(lmax, __shfl_xor(lmax, 16));
    lmax = fmaxf(lmax, __shfl_xor(lmax, 32));
    float s0 = lmax;

    // ---- phase 2: exp -> f16 LDS (per-wave buffer) -> f32 Mf regs ----
    // Same value path as R11: fexp2 result rounded to f16 once, then used
    // as f32 in all Sinkhorn math. acc is dead after the write block.
    {
        _Float16* buf = T[wave];
#pragma unroll
        for (int tm = 0; tm < 4; ++tm)
#pragma unroll
            for (int tn = 0; tn < 4; ++tn)
#pragma unroll
                for (int r = 0; r < 4; ++r) {
                    int row = tm * 16 + hi4 * 4 + r;
                    int col = tn * 16 + lo16;
                    int sp  = (col & 7) ^ (row >> 3);
                    buf[row * LDPH + (col & ~7) + sp] =
                        (_Float16)fexp2((acc[tm][tn][r] - s0) * K_SIM2M);
                }
    }
    __syncthreads();
    float Mf[8][8];
    {
        const _Float16* buf = T[wave];
#pragma unroll
        for (int t = 0; t < 8; ++t) {
            half8 h = *(const half8*)(buf + (ig * 8 + (jg ^ t)) * LDPH + jg * 8);
#pragma unroll
            for (int c = 0; c < 8; ++c) Mf[t][c] = (float)h[c];
        }
    }

    // ---- phase 3: Sinkhorn, reduce-scatter + all-gather, tol early exit ----
    int gp = q * 32 + w;
    float a_own = a_arr[(size_t)gp * 64 + ig * 8 + jg];
    float b_own = b_arr[((size_t)w * 256 + q) * 64 + jg * 8 + ig];

    float wvp[8];
#pragma unroll
    for (int s = 0; s < 8; ++s) wvp[s] = 1.0f;
    float q8[8];
    float w_prev = -1.f;

#pragma unroll 1
    for (int it = 0; it < 100; ++it) {
        float p[8];
#pragma unroll
        for (int t = 0; t < 8; ++t) {
            float s = Mf[t][0] * wvp[0];
#pragma unroll
            for (int c = 1; c < 8; ++c) s = fmaf(Mf[t][c], wvp[c], s);
            p[t] = s;
        }
        p[0] += __shfl_xor(p[4], 4); p[1] += __shfl_xor(p[5], 4);
        p[2] += __shfl_xor(p[6], 4); p[3] += __shfl_xor(p[7], 4);
        p[0] += __shfl_xor(p[2], 2); p[1] += __shfl_xor(p[3], 2);
        p[0] += __shfl_xor(p[1], 1);
        float z_own = a_own * fast_rcp(p[0]);
        q8[0] = z_own;
        q8[1] = __shfl_xor(q8[0], 1);
        q8[2] = __shfl_xor(q8[0], 2); q8[3] = __shfl_xor(q8[1], 2);
        q8[4] = __shfl_xor(q8[0], 4); q8[5] = __shfl_xor(q8[1], 4);
        q8[6] = __shfl_xor(q8[2], 4); q8[7] = __shfl_xor(q8[3], 4);
        float cp[8];
#pragma unroll
        for (int s = 0; s < 8; ++s) {
            float v = Mf[0][s] * q8[0];
#pragma unroll
            for (int t = 1; t < 8; ++t) v = fmaf(Mf[t][s], q8[t], v);
            cp[s] = v;
        }
        cp[0] += __shfl_xor(cp[4], 32); cp[1] += __shfl_xor(cp[5], 32);
        cp[2] += __shfl_xor(cp[6], 32); cp[3] += __shfl_xor(cp[7], 32);
        cp[0] += __shfl_xor(cp[2], 16); cp[1] += __shfl_xor(cp[3], 16);
        cp[0] += __shfl_xor(cp[1], 8);
        float w_own = b_own * fast_rcp(cp[0]);
        wvp[0] = w_own;
        wvp[1] = __shfl_xor(wvp[0], 8);
        wvp[2] = __shfl_xor(wvp[0], 16); wvp[3] = __shfl_xor(wvp[1], 16);
        wvp[4] = __shfl_xor(wvp[0], 32); wvp[5] = __shfl_xor(wvp[1], 32);
        wvp[6] = __shfl_xor(wvp[2], 32); wvp[7] = __shfl_xor(wvp[3], 32);
        // w stable across all 64 cols -> next z,w identical -> fixed point
        bool same = fabsf(w_own - w_prev) <= 1e-5f * w_own;
        w_prev = w_own;
        if (__all(same)) break;
    }

    // ---- phase 4: logits; sim = s0 + log2(M')*eps*ln2 ----
    float s = 0.f;
#pragma unroll
    for (int t = 0; t < 8; ++t)
#pragma unroll
        for (int c = 0; c < 8; ++c) {
            float m    = fmaxf(Mf[t][c], 1e-30f);
            float sim  = fmaf(flog2(m), K_M2SIM, s0);
            float flow = q8[t] * m * wvp[c];
            s = fmaf(sim, flow, s);
        }
    s += __shfl_xor(s, 1);  s += __shfl_xor(s, 2);  s += __shfl_xor(s, 4);
    s += __shfl_xor(s, 8);  s += __shfl_xor(s, 16); s += __shfl_xor(s, 32);
    if (lane == 0) out[gp] = s * 0.1953125f;   // 12.5/64
}

// ---------------------------------------------------------------------------
extern "C" void kernel_launch(void* const* d_in, const int* in_sizes, int n_in,
                              void* d_out, int out_size, void* d_ws, size_t ws_size,
                              hipStream_t stream) {
    (void)in_sizes; (void)n_in; (void)out_size; (void)ws_size;
    const float* support = (const float*)d_in[0];   // 32*512*64
    const float* query   = (const float*)d_in[1];   // 256*512*64

    char* ws = (char*)d_ws;
    _Float16* Uht = (_Float16*)ws;                  // 16 MB (fragment order)
    _Float16* Vht = Uht + 8388608;                  //  2 MB (fragment order)
    float* BpT  = (float*)(Vht + 1048576);          // 64 KB  [512][32]
    float* QpT  = BpT + 16384;                      // 512 KB [512][256]
    float* aA   = QpT + 131072;                     //  2 MB
    float* bA   = aA + 524288;                      //  2 MB
    float* muA  = bA + 524288;                      // 72 KB [288][64]
    float* nrmA = muA + 18432;                      // 72 KB
    float* Ssc  = nrmA + 18432;                     // ~1 KB [288]  (~23 MB total)

    norm_kernel<<<288, 1024, 0, stream>>>(support, query, Vht, Uht, BpT, QpT,
                                          muA, nrmA, Ssc);
    marg_kernel<<<512, 256, 0, stream>>>(Uht, Vht, BpT, QpT, muA, nrmA, Ssc,
                                         aA, bA);
    emd_kernel<<<2048, 256, 0, stream>>>(Uht, Vht, aA, bA, (float*)d_out);
}